// Round 17
// baseline (277.549 us; speedup 1.0000x reference)
//
#include <hip/hip_runtime.h>
#include <hip/hip_bf16.h>
#include <stdint.h>

#define N_NODES 100000
#define N_EDGES 1600000
#define TILE 8192
#define NB 196                                 // 196 buckets: bucket = id>>9
#define BIN_BLOCKS ((N_EDGES + TILE - 1) / TILE)   // 196

// ---- workspace layout (bytes) ----
static const size_t OFF_H      = 0;            // h bf16: 25,600,000
static const size_t OFF_SSCALE = 25600000;     // float 400,000
static const size_t OFF_ROWP   = 26000000;     // int 400,004
static const size_t OFF_RHIST  = 26400016;     // int 1024 (196 used)
static const size_t OFF_SHIST  = 26401040;     // int 1024 (contiguous w/ RHIST for memset)
static const size_t OFF_RBASE  = 26402064;     // int 1024
static const size_t OFF_SBASE  = 26403088;     // int 1024
static const size_t OFF_RCUR   = 26404112;     // int 1024
static const size_t OFF_SCUR   = 26405136;     // int 1024
static const size_t OFF_WFRAG  = 26406160;     // short8 x 2048 = 32,768 (16B aligned)
static const size_t OFF_EBUF   = 26438928;     // uint32 6,400,000
static const size_t OFF_SBUF   = 32838928;     // uint16 3,200,000 -> total ~36.04 MB

using short8 = __attribute__((ext_vector_type(8))) short;
using f32x4  = __attribute__((ext_vector_type(4))) float;

static __device__ __forceinline__ short f2bf(float f) {
    uint32_t u = __float_as_uint(f);
    uint32_t r = (u + 0x7fffu + ((u >> 16) & 1u)) >> 16;
    return (short)r;
}

// 0) pre-swizzle W into bf16 MFMA B-fragments (one-time, 2048 threads)
//    slot = f*64+lane; f = s*8+c; B[k=quad*8+j][n=c*16+mcol]
__global__ __launch_bounds__(256) void prep_w_kernel(const float* __restrict__ W,
                                                     short8* __restrict__ wfrag) {
    int slot = blockIdx.x * 256 + threadIdx.x;   // 0..2047
    int f = slot >> 6, lane = slot & 63;
    int quad = lane >> 4, mcol = lane & 15;
    int s = f >> 3, c = f & 7;
    int krow = s * 32 + quad * 8;
    int ncol = c * 16 + mcol;
    short8 wf;
    #pragma unroll
    for (int j = 0; j < 8; j++)
        wf[j] = f2bf(W[(krow + j) * 128 + ncol]);
    wfrag[slot] = wf;
}

// 1) coarse histograms (196 bins each for rcv>>9 and snd>>9), LDS-staged
__global__ __launch_bounds__(256) void hist196_kernel(const int* __restrict__ snd,
                                                      const int* __restrict__ rcv,
                                                      int* __restrict__ rhist,
                                                      int* __restrict__ shist) {
    __shared__ int hr[256], hs[256];
    int t = threadIdx.x;
    hr[t] = 0; hs[t] = 0;
    __syncthreads();
    int base = blockIdx.x * TILE;
    #pragma unroll
    for (int j = 0; j < 32; j++) {
        int idx = base + j * 256 + t;
        if (idx < N_EDGES) {
            atomicAdd(&hr[rcv[idx] >> 9], 1);
            atomicAdd(&hs[snd[idx] >> 9], 1);
        }
    }
    __syncthreads();
    if (t < NB) {
        if (hr[t]) atomicAdd(&rhist[t], hr[t]);
        if (hs[t]) atomicAdd(&shist[t], hs[t]);
    }
}

// 2) scan both 196-bucket histograms -> bases + working cursors
__global__ __launch_bounds__(256) void scanb_kernel(const int* __restrict__ rhist,
                                                    const int* __restrict__ shist,
                                                    int* __restrict__ rbase,
                                                    int* __restrict__ sbase,
                                                    int* __restrict__ rcur,
                                                    int* __restrict__ scur,
                                                    int* __restrict__ row_ptr) {
    __shared__ int s[256];
    int t = threadIdx.x;

    int v = (t < NB) ? rhist[t] : 0;
    s[t] = v;
    __syncthreads();
    #pragma unroll
    for (int off = 1; off < 256; off <<= 1) {
        int tv = (t >= off) ? s[t - off] : 0;
        __syncthreads();
        s[t] += tv;
        __syncthreads();
    }
    if (t < NB) { int e = s[t] - v; rbase[t] = e; rcur[t] = e; }
    __syncthreads();

    v = (t < NB) ? shist[t] : 0;
    s[t] = v;
    __syncthreads();
    #pragma unroll
    for (int off = 1; off < 256; off <<= 1) {
        int tv = (t >= off) ? s[t - off] : 0;
        __syncthreads();
        s[t] += tv;
        __syncthreads();
    }
    if (t < NB) { int e = s[t] - v; sbase[t] = e; scur[t] = e; }
    if (t == 0) row_ptr[N_NODES] = N_EDGES;
}

// 3) fused binning: r-channel packs (snd<<9|rcv&511) -> ebuf grouped by rcv>>9;
//    s-channel packs uint16(snd&511) -> sbuf grouped by snd>>9.
__global__ __launch_bounds__(256) void binr_kernel(const int* __restrict__ snd,
                                                   const int* __restrict__ rcv,
                                                   int* __restrict__ rcur,
                                                   int* __restrict__ scur,
                                                   uint32_t* __restrict__ ebuf,
                                                   uint16_t* __restrict__ sbuf) {
    __shared__ int hist[256];
    __shared__ int coff[256];
    __shared__ int ccur[256];
    __shared__ int gbase[256];
    __shared__ uint32_t stage[TILE];           // 32 KB

    const int t = threadIdx.x;
    const int base = blockIdx.x * TILE;

    uint32_t ss[32], rs[32];
    #pragma unroll
    for (int j = 0; j < 32; j++) {
        int idx = base + j * 256 + t;
        bool ok = idx < N_EDGES;
        ss[j] = ok ? (uint32_t)snd[idx] : 0u;
        rs[j] = ok ? (uint32_t)rcv[idx] : 0xffffffffu;
    }

    // ---------------- r-channel ----------------
    hist[t] = 0;
    __syncthreads();
    #pragma unroll
    for (int j = 0; j < 32; j++)
        if (rs[j] != 0xffffffffu) atomicAdd(&hist[rs[j] >> 9], 1);
    __syncthreads();

    int v = hist[t];
    ccur[t] = v;
    __syncthreads();
    #pragma unroll
    for (int off = 1; off < 256; off <<= 1) {
        int tv = (t >= off) ? ccur[t - off] : 0;
        __syncthreads();
        ccur[t] += tv;
        __syncthreads();
    }
    int excl = ccur[t] - v;
    coff[t] = excl;
    int gb = 0;
    if (v > 0) gb = atomicAdd(&rcur[t], v);
    gbase[t] = gb - excl;
    __syncthreads();
    ccur[t] = excl;
    __syncthreads();

    #pragma unroll
    for (int j = 0; j < 32; j++) {
        uint32_t r = rs[j];
        if (r != 0xffffffffu) {
            int pos = atomicAdd(&ccur[r >> 9], 1);
            stage[pos] = (ss[j] << 9) | (r & 511u);
        }
    }
    __syncthreads();

    int total = coff[255] + hist[255];
    for (int i = t; i < total; i += 256) {
        uint32_t pv = stage[i];
        int lo = 0;
        #pragma unroll
        for (int step = 128; step; step >>= 1)
            if (lo + step < 256 && coff[lo + step] <= i) lo += step;
        ebuf[gbase[lo] + i] = pv;
    }
    __syncthreads();

    // ---------------- s-channel ----------------
    hist[t] = 0;
    __syncthreads();
    #pragma unroll
    for (int j = 0; j < 32; j++)
        if (rs[j] != 0xffffffffu) atomicAdd(&hist[ss[j] >> 9], 1);
    __syncthreads();

    v = hist[t];
    ccur[t] = v;
    __syncthreads();
    #pragma unroll
    for (int off = 1; off < 256; off <<= 1) {
        int tv = (t >= off) ? ccur[t - off] : 0;
        __syncthreads();
        ccur[t] += tv;
        __syncthreads();
    }
    excl = ccur[t] - v;
    coff[t] = excl;
    gb = 0;
    if (v > 0) gb = atomicAdd(&scur[t], v);
    gbase[t] = gb - excl;
    __syncthreads();
    ccur[t] = excl;
    __syncthreads();

    uint16_t* stage16 = (uint16_t*)stage;
    #pragma unroll
    for (int j = 0; j < 32; j++) {
        if (rs[j] != 0xffffffffu) {
            int pos = atomicAdd(&ccur[ss[j] >> 9], 1);
            stage16[pos] = (uint16_t)(ss[j] & 511u);
        }
    }
    __syncthreads();

    total = coff[255] + hist[255];
    for (int i = t; i < total; i += 256) {
        uint16_t pv = stage16[i];
        int lo = 0;
        #pragma unroll
        for (int step = 128; step; step >>= 1)
            if (lo + step < 256 && coff[lo + step] <= i) lo += step;
        sbuf[gbase[lo] + i] = pv;
    }
}

// 4) per-bucket finalize: row_ptr + receiver-sort of senders + sender scale
__global__ __launch_bounds__(256) void bucket_kernel(const int* __restrict__ rbase,
                                                     const int* __restrict__ rhist,
                                                     const int* __restrict__ sbase,
                                                     const int* __restrict__ shist,
                                                     uint32_t* __restrict__ ebuf,
                                                     const uint16_t* __restrict__ sbuf,
                                                     int* __restrict__ row_ptr,
                                                     float* __restrict__ sscale) {
    __shared__ int hist_l[512];
    __shared__ int excl_l[512];
    __shared__ int cur_l[512];
    __shared__ int ps[256];
    __shared__ uint32_t inb[9216];
    __shared__ uint32_t perm[9216];

    const int b = blockIdx.x;
    const int t = threadIdx.x;
    const int nbase = b << 9;
    const int base = rbase[b];
    const int size = rhist[b];

    hist_l[t] = 0; hist_l[t + 256] = 0;
    __syncthreads();

    for (int i = t; i < size; i += 256) {
        uint32_t v = ebuf[base + i];
        inb[i] = v;
        atomicAdd(&hist_l[v & 511u], 1);
    }
    __syncthreads();

    int h0 = hist_l[2 * t], h1 = hist_l[2 * t + 1];
    int p = h0 + h1;
    ps[t] = p;
    __syncthreads();
    #pragma unroll
    for (int off = 1; off < 256; off <<= 1) {
        int tv = (t >= off) ? ps[t - off] : 0;
        __syncthreads();
        ps[t] += tv;
        __syncthreads();
    }
    int pe = ps[t] - p;
    excl_l[2 * t] = pe;
    excl_l[2 * t + 1] = pe + h0;
    cur_l[2 * t] = pe;
    cur_l[2 * t + 1] = pe + h0;
    __syncthreads();

    for (int i = t; i < 512; i += 256) {
        int n = nbase + i;
        if (n < N_NODES) row_ptr[n] = base + excl_l[i];
    }

    for (int i = t; i < size; i += 256) {
        uint32_t v = inb[i];
        int pos = atomicAdd(&cur_l[v & 511u], 1);
        perm[pos] = v >> 9;
    }
    __syncthreads();
    for (int i = t; i < size; i += 256)
        ebuf[base + i] = perm[i];

    __syncthreads();
    hist_l[t] = 0; hist_l[t + 256] = 0;
    __syncthreads();
    const int sb = sbase[b];
    const int ssz = shist[b];
    for (int i = t; i < ssz; i += 256)
        atomicAdd(&hist_l[(int)sbuf[sb + i]], 1);
    __syncthreads();
    for (int i = t; i < 512; i += 256) {
        int n = nbase + i;
        if (n < N_NODES) sscale[n] = rsqrtf(fmaxf((float)hist_l[i], 1.f));
    }
}

// 5) MFMA GEMM v3: B-fragments read straight from global (L2-resident 32 KB),
//    no LDS, no barriers. h[n][d] = bf16((x[n]·W[:,d] + bias[d]) * sscale[n])
//    Plain (coherent) loads — NT hints removed: they caused post-timing
//    divergence under the harness's poison/restore cycle (R16 bisect).
__global__ __launch_bounds__(256, 3) void gemm_mfma_kernel(const float* __restrict__ x,
                                                           const short8* __restrict__ wfrag,
                                                           const float* __restrict__ bias,
                                                           const float* __restrict__ sscale,
                                                           short* __restrict__ h) {
    const int t = threadIdx.x;
    const int lane = t & 63;
    const int wv = t >> 6;
    const int quad = lane >> 4;
    const int mcol = lane & 15;

    const int node0 = blockIdx.x * 128 + wv * 32;
    short8 afrag[2][4];
    #pragma unroll
    for (int mf = 0; mf < 2; mf++) {
        int node = node0 + mf * 16 + mcol;
        bool ok = node < N_NODES;
        const float* xr = x + (size_t)(ok ? node : 0) * 128;
        #pragma unroll
        for (int s = 0; s < 4; s++) {
            int k0 = s * 32 + quad * 8;
            f32x4 v0 = ok ? *(const f32x4*)(xr + k0)     : f32x4{0.f,0.f,0.f,0.f};
            f32x4 v1 = ok ? *(const f32x4*)(xr + k0 + 4) : f32x4{0.f,0.f,0.f,0.f};
            short8 af;
            #pragma unroll
            for (int j = 0; j < 4; j++) {
                af[j]     = f2bf(v0[j]);
                af[4 + j] = f2bf(v1[j]);
            }
            afrag[mf][s] = af;
        }
    }

    f32x4 acc[2][8];
    #pragma unroll
    for (int mf = 0; mf < 2; mf++)
        #pragma unroll
        for (int c = 0; c < 8; c++)
            acc[mf][c] = f32x4{0.f, 0.f, 0.f, 0.f};

    #pragma unroll
    for (int s = 0; s < 4; s++) {
        #pragma unroll
        for (int c = 0; c < 8; c++) {
            short8 bfrag = wfrag[(s * 8 + c) * 64 + lane];
            acc[0][c] = __builtin_amdgcn_mfma_f32_16x16x32_bf16(afrag[0][s], bfrag, acc[0][c], 0, 0, 0);
            acc[1][c] = __builtin_amdgcn_mfma_f32_16x16x32_bf16(afrag[1][s], bfrag, acc[1][c], 0, 0, 0);
        }
    }

    float rsv[2][4];
    #pragma unroll
    for (int mf = 0; mf < 2; mf++)
        #pragma unroll
        for (int r = 0; r < 4; r++) {
            int nd = node0 + mf * 16 + quad * 4 + r;
            rsv[mf][r] = (nd < N_NODES) ? sscale[nd] : 1.f;
        }

    #pragma unroll
    for (int mf = 0; mf < 2; mf++)
        #pragma unroll
        for (int c = 0; c < 8; c++) {
            float bval = bias[c * 16 + mcol];
            #pragma unroll
            for (int r = 0; r < 4; r++) {
                int nd = node0 + mf * 16 + quad * 4 + r;
                if (nd < N_NODES)
                    h[(size_t)nd * 128 + c * 16 + mcol] =
                        f2bf((acc[mf][c][r] + bval) * rsv[mf][r]);
            }
        }
}

// 6) gather v3: 4 nodes per wave (16 lanes x 8 dims via dwordx4), 4-deep unroll
//    -> 16 rows (4 KB) in flight per wave. Plain (coherent) f32x4 stores —
//    NT hints removed (R16 bisect: post-timing divergence under poison/restore).
__global__ __launch_bounds__(256) void gather_kernel(const uint32_t* __restrict__ h2,
                                                     const int* __restrict__ row_ptr,
                                                     const uint32_t* __restrict__ esrc,
                                                     f32x4* __restrict__ out4) {
    const int wv = threadIdx.x >> 6;       // wave in block: 0..3
    const int lane = threadIdx.x & 63;
    const int sub = lane >> 4;             // node within wave: 0..3
    const int ln = lane & 15;              // lane within node: 0..15
    const int node = blockIdx.x * 16 + wv * 4 + sub;

    const int b = row_ptr[node];
    const int e = row_ptr[node + 1];

    float a0 = 0.f, a1 = 0.f, a2 = 0.f, a3 = 0.f;
    float a4 = 0.f, a5 = 0.f, a6 = 0.f, a7 = 0.f;

    int i = b;
    for (; i + 4 <= e; i += 4) {
        uint32_t s0 = esrc[i + 0], s1 = esrc[i + 1], s2 = esrc[i + 2], s3 = esrc[i + 3];
        uint4 v0 = *(const uint4*)&h2[(size_t)s0 * 64 + ln * 4];
        uint4 v1 = *(const uint4*)&h2[(size_t)s1 * 64 + ln * 4];
        uint4 v2 = *(const uint4*)&h2[(size_t)s2 * 64 + ln * 4];
        uint4 v3 = *(const uint4*)&h2[(size_t)s3 * 64 + ln * 4];
        a0 += __uint_as_float(v0.x << 16) + __uint_as_float(v1.x << 16)
            + __uint_as_float(v2.x << 16) + __uint_as_float(v3.x << 16);
        a1 += __uint_as_float(v0.x & 0xffff0000u) + __uint_as_float(v1.x & 0xffff0000u)
            + __uint_as_float(v2.x & 0xffff0000u) + __uint_as_float(v3.x & 0xffff0000u);
        a2 += __uint_as_float(v0.y << 16) + __uint_as_float(v1.y << 16)
            + __uint_as_float(v2.y << 16) + __uint_as_float(v3.y << 16);
        a3 += __uint_as_float(v0.y & 0xffff0000u) + __uint_as_float(v1.y & 0xffff0000u)
            + __uint_as_float(v2.y & 0xffff0000u) + __uint_as_float(v3.y & 0xffff0000u);
        a4 += __uint_as_float(v0.z << 16) + __uint_as_float(v1.z << 16)
            + __uint_as_float(v2.z << 16) + __uint_as_float(v3.z << 16);
        a5 += __uint_as_float(v0.z & 0xffff0000u) + __uint_as_float(v1.z & 0xffff0000u)
            + __uint_as_float(v2.z & 0xffff0000u) + __uint_as_float(v3.z & 0xffff0000u);
        a6 += __uint_as_float(v0.w << 16) + __uint_as_float(v1.w << 16)
            + __uint_as_float(v2.w << 16) + __uint_as_float(v3.w << 16);
        a7 += __uint_as_float(v0.w & 0xffff0000u) + __uint_as_float(v1.w & 0xffff0000u)
            + __uint_as_float(v2.w & 0xffff0000u) + __uint_as_float(v3.w & 0xffff0000u);
    }
    for (; i < e; i++) {
        uint32_t s = esrc[i];
        uint4 v = *(const uint4*)&h2[(size_t)s * 64 + ln * 4];
        a0 += __uint_as_float(v.x << 16);
        a1 += __uint_as_float(v.x & 0xffff0000u);
        a2 += __uint_as_float(v.y << 16);
        a3 += __uint_as_float(v.y & 0xffff0000u);
        a4 += __uint_as_float(v.z << 16);
        a5 += __uint_as_float(v.z & 0xffff0000u);
        a6 += __uint_as_float(v.w << 16);
        a7 += __uint_as_float(v.w & 0xffff0000u);
    }
    float rs = rsqrtf(fmaxf((float)(e - b), 1.f));
    f32x4 o0 = {a0 * rs, a1 * rs, a2 * rs, a3 * rs};
    f32x4 o1 = {a4 * rs, a5 * rs, a6 * rs, a7 * rs};
    out4[(size_t)node * 32 + ln * 2 + 0] = o0;
    out4[(size_t)node * 32 + ln * 2 + 1] = o1;
}

extern "C" void kernel_launch(void* const* d_in, const int* in_sizes, int n_in,
                              void* d_out, int out_size, void* d_ws, size_t ws_size,
                              hipStream_t stream) {
    const float* x    = (const float*)d_in[0];
    const int*   snd  = (const int*)d_in[1];
    const int*   rcv  = (const int*)d_in[2];
    const float* W    = (const float*)d_in[4];
    const float* bias = (const float*)d_in[5];

    char* ws = (char*)d_ws;
    short*    h      = (short*)(ws + OFF_H);
    float*    sscale = (float*)(ws + OFF_SSCALE);
    int*      rowp   = (int*)(ws + OFF_ROWP);
    int*      rhist  = (int*)(ws + OFF_RHIST);
    int*      shist  = (int*)(ws + OFF_SHIST);
    int*      rbase  = (int*)(ws + OFF_RBASE);
    int*      sbase  = (int*)(ws + OFF_SBASE);
    int*      rcur   = (int*)(ws + OFF_RCUR);
    int*      scur   = (int*)(ws + OFF_SCUR);
    short8*   wfrag  = (short8*)(ws + OFF_WFRAG);
    uint32_t* ebuf   = (uint32_t*)(ws + OFF_EBUF);
    uint16_t* sbuf   = (uint16_t*)(ws + OFF_SBUF);

    hipMemsetAsync(ws + OFF_RHIST, 0, 2048, stream);   // rhist + shist

    prep_w_kernel  <<<8, 256, 0, stream>>>(W, wfrag);
    hist196_kernel <<<BIN_BLOCKS, 256, 0, stream>>>(snd, rcv, rhist, shist);
    scanb_kernel   <<<1, 256, 0, stream>>>(rhist, shist, rbase, sbase, rcur, scur, rowp);
    binr_kernel    <<<BIN_BLOCKS, 256, 0, stream>>>(snd, rcv, rcur, scur, ebuf, sbuf);
    bucket_kernel  <<<NB, 256, 0, stream>>>(rbase, rhist, sbase, shist, ebuf, sbuf, rowp, sscale);
    gemm_mfma_kernel<<<(N_NODES + 127) / 128, 256, 0, stream>>>(x, wfrag, bias, sscale, h);
    gather_kernel  <<<N_NODES / 16, 256, 0, stream>>>((const uint32_t*)h, rowp, ebuf, (f32x4*)d_out);
}